// Round 1
// baseline (215.428 us; speedup 1.0000x reference)
//
#include <hip/hip_runtime.h>

// Problem geometry (fixed by the reference): x [B=2, C=64, R_rot=6, charts=5, H=128, W=256] fp32.
#define RROT   6
#define CHARTS 5
#define HDIM   128
#define WDIM   256

// Strides (elements)
#define CHART_STRIDE ((long long)HDIM * WDIM)            // 32768
#define ROT_STRIDE   ((long long)CHARTS * CHART_STRIDE)  // 163840
#define BC_STRIDE    ((long long)RROT * ROT_STRIDE)      // 983040

// One thread per (b*c, chart): compute m1 (pole at col 0) and m2 (pole at col 128)
// as means over 6 rotations x 5 neighbors, then write them into out for all 6 rotations.
// Neighbors never hit the pole positions, so reading the raw input is correct.
__global__ void SmoothVertices_pole_fix(const float* __restrict__ x,
                                        float* __restrict__ out,
                                        int total /* BC*CHARTS */) {
    int idx = blockIdx.x * blockDim.x + threadIdx.x;
    if (idx >= total) return;
    int c  = idx % CHARTS;
    int bc = idx / CHARTS;
    int cm = (c + CHARTS - 1) % CHARTS;  // (c-1) mod 5

    const float* base = x + (long long)bc * BC_STRIDE;

    // V1 neighbors of pole (0,0): [c,1,0],[c,1,1],[c,0,1],[cm,127,128],[cm,127,127]
    const long long off1[5] = {
        (long long)c  * CHART_STRIDE + 1 * WDIM + 0,
        (long long)c  * CHART_STRIDE + 1 * WDIM + 1,
        (long long)c  * CHART_STRIDE + 0 * WDIM + 1,
        (long long)cm * CHART_STRIDE + 127 * WDIM + 128,
        (long long)cm * CHART_STRIDE + 127 * WDIM + 127,
    };
    // V2 neighbors of pole (0,128): [c,1,128],[c,1,129],[c,0,129],[cm,127,255],[c,0,127]
    const long long off2[5] = {
        (long long)c  * CHART_STRIDE + 1 * WDIM + 128,
        (long long)c  * CHART_STRIDE + 1 * WDIM + 129,
        (long long)c  * CHART_STRIDE + 0 * WDIM + 129,
        (long long)cm * CHART_STRIDE + 127 * WDIM + 255,
        (long long)c  * CHART_STRIDE + 0 * WDIM + 127,
    };

    float s1 = 0.0f, s2 = 0.0f;
    #pragma unroll
    for (int r = 0; r < RROT; ++r) {
        const float* rb = base + (long long)r * ROT_STRIDE;
        #pragma unroll
        for (int n = 0; n < 5; ++n) {
            s1 += rb[off1[n]];
            s2 += rb[off2[n]];
        }
    }
    const float inv = 1.0f / (float)(RROT * 5);
    float m1 = s1 * inv;
    float m2 = s2 * inv;

    float* obase = out + (long long)bc * BC_STRIDE + (long long)c * CHART_STRIDE;
    #pragma unroll
    for (int r = 0; r < RROT; ++r) {
        obase[(long long)r * ROT_STRIDE + 0]   = m1;
        obase[(long long)r * ROT_STRIDE + 128] = m2;
    }
}

extern "C" void kernel_launch(void* const* d_in, const int* in_sizes, int n_in,
                              void* d_out, int out_size, void* d_ws, size_t ws_size,
                              hipStream_t stream) {
    const float* x = (const float*)d_in[0];
    float* out = (float*)d_out;

    // Bulk copy: output == input except 12 entries per (bc,chart).
    size_t nbytes = (size_t)out_size * sizeof(float);
    hipMemcpyAsync(out, x, nbytes, hipMemcpyDeviceToDevice, stream);

    // Fix-up: one thread per (bc, chart). BC = B*C = total / (RROT*CHARTS*H*W).
    int bc = (int)((long long)in_sizes[0] / BC_STRIDE);  // 128
    int total = bc * CHARTS;                              // 640
    int threads = 128;
    int blocks = (total + threads - 1) / threads;         // 5
    SmoothVertices_pole_fix<<<blocks, threads, 0, stream>>>(x, out, total);
}